// Round 2
// baseline (1183.127 us; speedup 1.0000x reference)
//
#include <hip/hip_runtime.h>
#include <hip/hip_bf16.h>
#include <math.h>

#define NNODES 50000
#define NEDGE 625000
#define RREL 16

typedef __attribute__((ext_vector_type(8))) short short8;
typedef __attribute__((ext_vector_type(4))) float f32x4;

__device__ __forceinline__ float bfu(ushort u) {
  return __uint_as_float(((unsigned)u) << 16);
}

// ---------------- weight prep: bf16, B stored transposed (N x K, K contiguous) ----
// BTqkv: 384x128 = in_proj_w as-is (it's (3E,E) row-major = N-major already)
// BTout: 128x128 = out_proj_w as-is
// BT1: 1088x128  row c: c<64 -> root1[k*64+c]; else r=(c-64)>>6,o=(c-64)&63 -> w1[r][k][o]
// BT2: 544x64    row c: c<32 -> root2[k*32+c]; else r=(c-32)>>5,o=(c-32)&31 -> w2[r][k][o]
__global__ __launch_bounds__(256) void prep_weights(
    const float* __restrict__ ipw, const float* __restrict__ opw,
    const float* __restrict__ w1, const float* __restrict__ root1,
    const float* __restrict__ w2, const float* __restrict__ root2,
    __hip_bfloat16* __restrict__ BTqkv, __hip_bfloat16* __restrict__ BTout,
    __hip_bfloat16* __restrict__ BT1, __hip_bfloat16* __restrict__ BT2) {
  int i = blockIdx.x * 256 + threadIdx.x;
  if (i < 49152) {
    BTqkv[i] = __float2bfloat16(ipw[i]);
  } else if (i < 65536) {
    int j = i - 49152;
    BTout[j] = __float2bfloat16(opw[j]);
  } else if (i < 65536 + 139264) {
    int j = i - 65536; int c = j / 128, k = j % 128;
    float v;
    if (c < 64) v = root1[k * 64 + c];
    else { int r = (c - 64) >> 6, o = (c - 64) & 63; v = w1[r * 8192 + k * 64 + o]; }
    BT1[j] = __float2bfloat16(v);
  } else if (i < 65536 + 139264 + 34816) {
    int j = i - 65536 - 139264; int c = j / 64, k = j % 64;
    float v;
    if (c < 32) v = root2[k * 32 + c];
    else { int r = (c - 32) >> 5, o = (c - 32) & 31; v = w2[r * 2048 + k * 32 + o]; }
    BT2[j] = __float2bfloat16(v);
  }
}

// ---------------- f32 -> bf16 convert (8 elems/thread) ----------------------------
__global__ __launch_bounds__(256) void f2b_kernel(
    const float* __restrict__ in, __hip_bfloat16* __restrict__ out) {
  size_t i = (size_t)(blockIdx.x * 256 + threadIdx.x) * 8;
  float4 a = *(const float4*)(in + i);
  float4 b = *(const float4*)(in + i + 4);
  ushort u[8];
  float f[8] = {a.x, a.y, a.z, a.w, b.x, b.y, b.z, b.w};
#pragma unroll
  for (int j = 0; j < 8; j++) {
    __hip_bfloat16 h = __float2bfloat16(f[j]);
    u[j] = *(ushort*)&h;
  }
  *(ushort4*)((ushort*)out + i) = make_ushort4(u[0], u[1], u[2], u[3]);
  *(ushort4*)((ushort*)out + i + 4) = make_ushort4(u[4], u[5], u[6], u[7]);
}

// ---------------- bf16 MFMA GEMM: C[M,N] = A[M,K] @ BT[N,K]^T (+bias) -------------
// 128x128 tile, 4 waves (2x2), each wave 64x64 via 4x4 frags of 16x16x32.
// Full-K LDS panels (K<=128), XOR-swizzled 16B chunks.
template <int K>
__global__ __launch_bounds__(256) void gemm_mfma(
    const __hip_bfloat16* __restrict__ A, const __hip_bfloat16* __restrict__ BT,
    const float* __restrict__ bias, __hip_bfloat16* __restrict__ C,
    int M, int N, int lda, int ldc) {
  constexpr int CPR = K / 8;  // 16B chunks per row
  __shared__ ushort As[128 * K];
  __shared__ ushort Bs[128 * K];
  const int t = threadIdx.x;
  const long row0 = (long)blockIdx.x * 128;
  const int col0 = blockIdx.y * 128;

#pragma unroll
  for (int c = t; c < 128 * CPR; c += 256) {
    int r = c / CPR, cc = c % CPR;
    long gm = row0 + r;
    int4 v = make_int4(0, 0, 0, 0);
    if (gm < M) v = *(const int4*)(A + gm * lda + cc * 8);
    *(int4*)(As + r * K + ((cc ^ (r & 7)) * 8)) = v;
  }
#pragma unroll
  for (int c = t; c < 128 * CPR; c += 256) {
    int r = c / CPR, cc = c % CPR;
    int gn = col0 + r;
    int4 v = make_int4(0, 0, 0, 0);
    if (gn < N) v = *(const int4*)(BT + (long)gn * K + cc * 8);
    *(int4*)(Bs + r * K + ((cc ^ (r & 7)) * 8)) = v;
  }
  __syncthreads();

  const int lane = t & 63, w = t >> 6;
  const int wr = (w >> 1) * 64, wc = (w & 1) * 64;
  const int lrow = lane & 15, lk = lane >> 4;
  f32x4 acc[4][4];
#pragma unroll
  for (int i = 0; i < 4; i++)
#pragma unroll
    for (int j = 0; j < 4; j++) acc[i][j] = (f32x4){0.f, 0.f, 0.f, 0.f};

#pragma unroll
  for (int k0 = 0; k0 < K; k0 += 32) {
    const int cb = k0 / 8 + lk;
    short8 af[4], bfr[4];
#pragma unroll
    for (int i = 0; i < 4; i++) {
      int ra = wr + i * 16 + lrow;
      af[i] = *(const short8*)(As + ra * K + ((cb ^ (ra & 7)) * 8));
      int rb = wc + i * 16 + lrow;
      bfr[i] = *(const short8*)(Bs + rb * K + ((cb ^ (rb & 7)) * 8));
    }
#pragma unroll
    for (int i = 0; i < 4; i++)
#pragma unroll
      for (int j = 0; j < 4; j++)
        acc[i][j] = __builtin_amdgcn_mfma_f32_16x16x32_bf16(af[i], bfr[j], acc[i][j], 0, 0, 0);
  }

  // epilogue: C/D layout col=lane&15, row=(lane>>4)*4+q
#pragma unroll
  for (int j = 0; j < 4; j++) {
    int col = col0 + wc + j * 16 + lrow;
    if (col < N) {
      float bv = bias ? bias[col] : 0.f;
#pragma unroll
      for (int i = 0; i < 4; i++) {
        long rbase = row0 + wr + i * 16 + lk * 4;
#pragma unroll
        for (int q = 0; q < 4; q++) {
          long rr = rbase + q;
          if (rr < M) C[rr * ldc + col] = __float2bfloat16(acc[i][j][q] + bv);
        }
      }
    }
  }
}

// ---------------- attention (only l=0 of output needed) ---------------------------
// kv layout: kv[(m*NNODES+n)*256 + c], c<128 -> k, else v. Block: 2 nodes x 128 ch.
__global__ __launch_bounds__(256) void attn_kernel(
    const __hip_bfloat16* __restrict__ q0, const __hip_bfloat16* __restrict__ kv,
    __hip_bfloat16* __restrict__ o0) {
  int t = threadIdx.x;
  int n = blockIdx.x * 2 + (t >> 7);
  int ch = t & 127;
  size_t base = (size_t)n * 128 + ch;
  float q = __bfloat162float(q0[base]);
  float s[4];
#pragma unroll
  for (int m = 0; m < 4; m++) {
    float kk = __bfloat162float(kv[((size_t)(m * NNODES + n)) * 256 + ch]);
    float p = q * kk;
#pragma unroll
    for (int off = 16; off; off >>= 1) p += __shfl_xor(p, off);
    s[m] = p * 0.17677669529663687f;  // 1/sqrt(32)
  }
  float mx = fmaxf(fmaxf(s[0], s[1]), fmaxf(s[2], s[3]));
  float e[4], sum = 0.f;
#pragma unroll
  for (int m = 0; m < 4; m++) { e[m] = __expf(s[m] - mx); sum += e[m]; }
  float inv = 1.0f / sum;
  float out = 0.f;
#pragma unroll
  for (int m = 0; m < 4; m++)
    out += e[m] * inv * __bfloat162float(kv[((size_t)(m * NNODES + n)) * 256 + 128 + ch]);
  o0[base] = __float2bfloat16(out);
}

// ---------------- edge counts -----------------------------------------------------
__global__ __launch_bounds__(256) void count_edges(
    const int* __restrict__ dst, const int* __restrict__ et, int* __restrict__ cnt) {
  int e = blockIdx.x * 256 + threadIdx.x;
  if (e < NEDGE) atomicAdd(&cnt[et[e] * NNODES + dst[e]], 1);
}

// ---------------- layer1 ----------------------------------------------------------
__global__ __launch_bounds__(256) void init1(
    const __hip_bfloat16* __restrict__ Y1, const float* __restrict__ b1,
    float* __restrict__ x1) {
  int i = blockIdx.x * 256 + threadIdx.x;  // NNODES*64 exact
  int n = i >> 6, j = i & 63;
  x1[i] = __bfloat162float(Y1[(size_t)n * 1088 + j]) + b1[j];
}

__global__ __launch_bounds__(256) void agg1(
    const int* __restrict__ src, const int* __restrict__ dst, const int* __restrict__ et,
    const int* __restrict__ cnt, const ushort* __restrict__ Y1, float* __restrict__ x1) {
  int t = blockIdx.x * 256 + threadIdx.x;
  int e = t >> 4;
  if (e >= NEDGE) return;
  int j4 = (t & 15) * 4;
  int s = src[e], d = dst[e], r = et[e];
  float sc = 1.0f / (float)cnt[r * NNODES + d];
  ushort4 v = *(const ushort4*)(Y1 + (size_t)s * 1088 + 64 + r * 64 + j4);
  float* xp = x1 + (size_t)d * 64 + j4;
  atomicAdd(xp + 0, bfu(v.x) * sc);
  atomicAdd(xp + 1, bfu(v.y) * sc);
  atomicAdd(xp + 2, bfu(v.z) * sc);
  atomicAdd(xp + 3, bfu(v.w) * sc);
}

__global__ __launch_bounds__(256) void relu1b(
    const float* __restrict__ x1, __hip_bfloat16* __restrict__ x1b) {
  int i = blockIdx.x * 256 + threadIdx.x;  // NNODES*64 exact
  x1b[i] = __float2bfloat16(fmaxf(x1[i], 0.f));
}

// ---------------- layer2 ----------------------------------------------------------
__global__ __launch_bounds__(256) void init2(
    const __hip_bfloat16* __restrict__ Y2, const float* __restrict__ b2,
    float* __restrict__ a2) {
  int i = blockIdx.x * 256 + threadIdx.x;  // NNODES*32 exact
  int n = i >> 5, j = i & 31;
  a2[i] = __bfloat162float(Y2[(size_t)n * 544 + j]) + b2[j];
}

__global__ __launch_bounds__(256) void agg2(
    const int* __restrict__ src, const int* __restrict__ dst, const int* __restrict__ et,
    const int* __restrict__ cnt, const ushort* __restrict__ Y2, float* __restrict__ a2) {
  int t = blockIdx.x * 256 + threadIdx.x;
  int e = t >> 3;
  if (e >= NEDGE) return;
  int j4 = (t & 7) * 4;
  int s = src[e], d = dst[e], r = et[e];
  float sc = 1.0f / (float)cnt[r * NNODES + d];
  ushort4 v = *(const ushort4*)(Y2 + (size_t)s * 544 + 32 + r * 32 + j4);
  float* ap = a2 + (size_t)d * 32 + j4;
  atomicAdd(ap + 0, bfu(v.x) * sc);
  atomicAdd(ap + 1, bfu(v.y) * sc);
  atomicAdd(ap + 2, bfu(v.z) * sc);
  atomicAdd(ap + 3, bfu(v.w) * sc);
}

__global__ __launch_bounds__(256) void softmax_out(
    const float* __restrict__ a2, float* __restrict__ out) {
  int t = blockIdx.x * 256 + threadIdx.x;  // NNODES*32 exact
  int n = t >> 5, lane = t & 31;
  float v = a2[(size_t)n * 32 + lane];
  float mx = v;
#pragma unroll
  for (int off = 16; off; off >>= 1) mx = fmaxf(mx, __shfl_xor(mx, off));
  float e = __expf(v - mx);
  float sum = e;
#pragma unroll
  for (int off = 16; off; off >>= 1) sum += __shfl_xor(sum, off);
  out[(size_t)n * 32 + lane] = e / sum;
}

// =================================================================================
extern "C" void kernel_launch(void* const* d_in, const int* in_sizes, int n_in,
                              void* d_out, int out_size, void* d_ws, size_t ws_size,
                              hipStream_t stream) {
  (void)in_sizes; (void)n_in; (void)out_size; (void)ws_size;
  const float* emb   = (const float*)d_in[0];
  const float* ipw   = (const float*)d_in[1];
  const float* ipb   = (const float*)d_in[2];
  const float* opw   = (const float*)d_in[3];
  const float* opb   = (const float*)d_in[4];
  const float* w1    = (const float*)d_in[5];
  const float* root1 = (const float*)d_in[6];
  const float* b1    = (const float*)d_in[7];
  const float* w2    = (const float*)d_in[8];
  const float* root2 = (const float*)d_in[9];
  const float* b2    = (const float*)d_in[10];
  const int*   eidx  = (const int*)d_in[11];
  const int*   etype = (const int*)d_in[12];
  const int* srcp = eidx;
  const int* dstp = eidx + NEDGE;

  unsigned char* ws = (unsigned char*)d_ws;
  size_t off = 0;
  auto alloc = [&](size_t bytes) {
    unsigned char* p = ws + off;
    off += (bytes + 255) & ~(size_t)255;
    return p;
  };

  // Region R reused sequentially: [embb 51.2MB | kv 102.4MB] -> Y1 108.8MB -> Y2 54.4MB
  unsigned char* R = alloc(153600000);
  __hip_bfloat16* embb = (__hip_bfloat16*)R;
  __hip_bfloat16* kv   = (__hip_bfloat16*)(R + 51200000);
  __hip_bfloat16* Y1   = (__hip_bfloat16*)R;
  __hip_bfloat16* Y2   = (__hip_bfloat16*)R;
  __hip_bfloat16* q0   = (__hip_bfloat16*)alloc(12800000);
  __hip_bfloat16* o0   = (__hip_bfloat16*)alloc(12800000);
  __hip_bfloat16* x0   = (__hip_bfloat16*)alloc(12800000);
  float*          x1   = (float*)alloc(12800000);
  __hip_bfloat16* x1b  = (__hip_bfloat16*)alloc(6400000);
  float*          a2   = (float*)alloc(6400000);
  int*            cnt  = (int*)alloc(3200000);
  __hip_bfloat16* BTqkv = (__hip_bfloat16*)alloc(98304);
  __hip_bfloat16* BTout = (__hip_bfloat16*)alloc(32768);
  __hip_bfloat16* BT1   = (__hip_bfloat16*)alloc(278528);
  __hip_bfloat16* BT2   = (__hip_bfloat16*)alloc(69632);

  // 1) weight prep + input convert + edge counts (independent of GEMMs)
  prep_weights<<<dim3((241664 + 255) / 256), dim3(256), 0, stream>>>(
      ipw, opw, w1, root1, w2, root2, BTqkv, BTout, BT1, BT2);
  f2b_kernel<<<dim3(12500), dim3(256), 0, stream>>>(emb, embb);
  hipMemsetAsync(cnt, 0, (size_t)RREL * NNODES * sizeof(int), stream);
  count_edges<<<dim3((NEDGE + 255) / 256), dim3(256), 0, stream>>>(dstp, etype, cnt);

  // 2) KV projection: (200000 x 128) @ (128 x 256) -> kv
  gemm_mfma<128><<<dim3(1563, 2), dim3(256), 0, stream>>>(
      embb, BTqkv + 128 * 128, ipb + 128, kv, 200000, 256, 128, 256);

  // 3) Q at l=0: (50000 x 128) @ (128 x 128) -> q0
  gemm_mfma<128><<<dim3(391, 1), dim3(256), 0, stream>>>(
      embb, BTqkv, ipb, q0, NNODES, 128, 128, 128);

  // 4) attention -> o0
  attn_kernel<<<dim3(25000), dim3(256), 0, stream>>>(q0, kv, o0);

  // 5) out_proj -> x0
  gemm_mfma<128><<<dim3(391, 1), dim3(256), 0, stream>>>(
      o0, BTout, opb, x0, NNODES, 128, 128, 128);

  // 6) Y1 = x0 @ [root1 | W1_r]: (50000 x 128) @ (128 x 1088)
  gemm_mfma<128><<<dim3(391, 9), dim3(256), 0, stream>>>(
      x0, BT1, nullptr, Y1, NNODES, 1088, 128, 1088);

  // 7) layer1: init + aggregate + relu->bf16
  init1<<<dim3(NNODES * 64 / 256), dim3(256), 0, stream>>>(Y1, b1, x1);
  agg1<<<dim3((NEDGE * 16 + 255) / 256), dim3(256), 0, stream>>>(
      srcp, dstp, etype, cnt, (const ushort*)Y1, x1);
  relu1b<<<dim3(NNODES * 64 / 256), dim3(256), 0, stream>>>(x1, x1b);

  // 8) Y2 = x1 @ [root2 | W2_r]: (50000 x 64) @ (64 x 544)
  gemm_mfma<64><<<dim3(391, 5), dim3(256), 0, stream>>>(
      x1b, BT2, nullptr, Y2, NNODES, 544, 64, 544);

  // 9) layer2: init + aggregate + softmax
  init2<<<dim3(NNODES * 32 / 256), dim3(256), 0, stream>>>(Y2, b2, a2);
  agg2<<<dim3((NEDGE * 8 + 255) / 256), dim3(256), 0, stream>>>(
      srcp, dstp, etype, cnt, (const ushort*)Y2, a2);
  softmax_out<<<dim3(NNODES * 32 / 256), dim3(256), 0, stream>>>(a2, (float*)d_out);
}

// Round 3
// 530.295 us; speedup vs baseline: 2.2311x; 2.2311x over previous
//
#include <hip/hip_runtime.h>
#include <hip/hip_bf16.h>
#include <math.h>

#define NNODES 50000
#define NEDGE 625000
#define RREL 16
#define SCAN_NB 196   // ceil(50000/256)

typedef __attribute__((ext_vector_type(8))) short short8;
typedef __attribute__((ext_vector_type(4))) float f32x4;

__device__ __forceinline__ float bfu(ushort u) {
  return __uint_as_float(((unsigned)u) << 16);
}

// ---------------- weight prep: bf16, B stored transposed (N x K, K contiguous) ----
__global__ __launch_bounds__(256) void prep_weights(
    const float* __restrict__ ipw, const float* __restrict__ opw,
    const float* __restrict__ w1, const float* __restrict__ root1,
    const float* __restrict__ w2, const float* __restrict__ root2,
    __hip_bfloat16* __restrict__ BTqkv, __hip_bfloat16* __restrict__ BTout,
    __hip_bfloat16* __restrict__ BT1, __hip_bfloat16* __restrict__ BT2) {
  int i = blockIdx.x * 256 + threadIdx.x;
  if (i < 49152) {
    BTqkv[i] = __float2bfloat16(ipw[i]);
  } else if (i < 65536) {
    int j = i - 49152;
    BTout[j] = __float2bfloat16(opw[j]);
  } else if (i < 65536 + 139264) {
    int j = i - 65536; int c = j / 128, k = j % 128;
    float v;
    if (c < 64) v = root1[k * 64 + c];
    else { int r = (c - 64) >> 6, o = (c - 64) & 63; v = w1[r * 8192 + k * 64 + o]; }
    BT1[j] = __float2bfloat16(v);
  } else if (i < 65536 + 139264 + 34816) {
    int j = i - 65536 - 139264; int c = j / 64, k = j % 64;
    float v;
    if (c < 32) v = root2[k * 32 + c];
    else { int r = (c - 32) >> 5, o = (c - 32) & 31; v = w2[r * 2048 + k * 32 + o]; }
    BT2[j] = __float2bfloat16(v);
  }
}

// ---------------- f32 -> bf16 convert (8 elems/thread) ----------------------------
__global__ __launch_bounds__(256) void f2b_kernel(
    const float* __restrict__ in, __hip_bfloat16* __restrict__ out) {
  size_t i = (size_t)(blockIdx.x * 256 + threadIdx.x) * 8;
  float4 a = *(const float4*)(in + i);
  float4 b = *(const float4*)(in + i + 4);
  ushort u[8];
  float f[8] = {a.x, a.y, a.z, a.w, b.x, b.y, b.z, b.w};
#pragma unroll
  for (int j = 0; j < 8; j++) {
    __hip_bfloat16 h = __float2bfloat16(f[j]);
    u[j] = *(ushort*)&h;
  }
  *(ushort4*)((ushort*)out + i) = make_ushort4(u[0], u[1], u[2], u[3]);
  *(ushort4*)((ushort*)out + i + 4) = make_ushort4(u[4], u[5], u[6], u[7]);
}

// ---------------- bf16 MFMA GEMM: C[M,N] = A[M,K] @ BT[N,K]^T (+bias) -------------
template <int K>
__global__ __launch_bounds__(256) void gemm_mfma(
    const __hip_bfloat16* __restrict__ A, const __hip_bfloat16* __restrict__ BT,
    const float* __restrict__ bias, __hip_bfloat16* __restrict__ C,
    int M, int N, int lda, int ldc) {
  constexpr int CPR = K / 8;
  __shared__ ushort As[128 * K];
  __shared__ ushort Bs[128 * K];
  const int t = threadIdx.x;
  const long row0 = (long)blockIdx.x * 128;
  const int col0 = blockIdx.y * 128;

#pragma unroll
  for (int c = t; c < 128 * CPR; c += 256) {
    int r = c / CPR, cc = c % CPR;
    long gm = row0 + r;
    int4 v = make_int4(0, 0, 0, 0);
    if (gm < M) v = *(const int4*)(A + gm * lda + cc * 8);
    *(int4*)(As + r * K + ((cc ^ (r & 7)) * 8)) = v;
  }
#pragma unroll
  for (int c = t; c < 128 * CPR; c += 256) {
    int r = c / CPR, cc = c % CPR;
    int gn = col0 + r;
    int4 v = make_int4(0, 0, 0, 0);
    if (gn < N) v = *(const int4*)(BT + (long)gn * K + cc * 8);
    *(int4*)(Bs + r * K + ((cc ^ (r & 7)) * 8)) = v;
  }
  __syncthreads();

  const int lane = t & 63, w = t >> 6;
  const int wr = (w >> 1) * 64, wc = (w & 1) * 64;
  const int lrow = lane & 15, lk = lane >> 4;
  f32x4 acc[4][4];
#pragma unroll
  for (int i = 0; i < 4; i++)
#pragma unroll
    for (int j = 0; j < 4; j++) acc[i][j] = (f32x4){0.f, 0.f, 0.f, 0.f};

#pragma unroll
  for (int k0 = 0; k0 < K; k0 += 32) {
    const int cb = k0 / 8 + lk;
    short8 af[4], bfr[4];
#pragma unroll
    for (int i = 0; i < 4; i++) {
      int ra = wr + i * 16 + lrow;
      af[i] = *(const short8*)(As + ra * K + ((cb ^ (ra & 7)) * 8));
      int rb = wc + i * 16 + lrow;
      bfr[i] = *(const short8*)(Bs + rb * K + ((cb ^ (rb & 7)) * 8));
    }
#pragma unroll
    for (int i = 0; i < 4; i++)
#pragma unroll
      for (int j = 0; j < 4; j++)
        acc[i][j] = __builtin_amdgcn_mfma_f32_16x16x32_bf16(af[i], bfr[j], acc[i][j], 0, 0, 0);
  }

#pragma unroll
  for (int j = 0; j < 4; j++) {
    int col = col0 + wc + j * 16 + lrow;
    if (col < N) {
      float bv = bias ? bias[col] : 0.f;
#pragma unroll
      for (int i = 0; i < 4; i++) {
        long rbase = row0 + wr + i * 16 + lk * 4;
#pragma unroll
        for (int q = 0; q < 4; q++) {
          long rr = rbase + q;
          if (rr < M) C[rr * ldc + col] = __float2bfloat16(acc[i][j][q] + bv);
        }
      }
    }
  }
}

// ---------------- attention (only l=0 of output needed) ---------------------------
__global__ __launch_bounds__(256) void attn_kernel(
    const __hip_bfloat16* __restrict__ q0, const __hip_bfloat16* __restrict__ kv,
    __hip_bfloat16* __restrict__ o0) {
  int t = threadIdx.x;
  int n = blockIdx.x * 2 + (t >> 7);
  int ch = t & 127;
  size_t base = (size_t)n * 128 + ch;
  float q = __bfloat162float(q0[base]);
  float s[4];
#pragma unroll
  for (int m = 0; m < 4; m++) {
    float kk = __bfloat162float(kv[((size_t)(m * NNODES + n)) * 256 + ch]);
    float p = q * kk;
#pragma unroll
    for (int off = 16; off; off >>= 1) p += __shfl_xor(p, off);
    s[m] = p * 0.17677669529663687f;
  }
  float mx = fmaxf(fmaxf(s[0], s[1]), fmaxf(s[2], s[3]));
  float e[4], sum = 0.f;
#pragma unroll
  for (int m = 0; m < 4; m++) { e[m] = __expf(s[m] - mx); sum += e[m]; }
  float inv = 1.0f / sum;
  float out = 0.f;
#pragma unroll
  for (int m = 0; m < 4; m++)
    out += e[m] * inv * __bfloat162float(kv[((size_t)(m * NNODES + n)) * 256 + 128 + ch]);
  o0[base] = __float2bfloat16(out);
}

// ---------------- edge counts per (r, dst) ---------------------------------------
__global__ __launch_bounds__(256) void count_edges(
    const int* __restrict__ dst, const int* __restrict__ et, int* __restrict__ cnt) {
  int e = blockIdx.x * 256 + threadIdx.x;
  if (e < NEDGE) atomicAdd(&cnt[et[e] * NNODES + dst[e]], 1);
}

// ---------------- CSR build: scan of per-dst degree, then scatter ----------------
// scan1: hd[i] = sum_r cnt[r*N+i]; block-exclusive-scan -> off[i]; block sums -> part
__global__ __launch_bounds__(256) void scan1(
    const int* __restrict__ cnt, int* __restrict__ off, int* __restrict__ part) {
  int t = threadIdx.x, b = blockIdx.x;
  int i = b * 256 + t;
  int v = 0;
  if (i < NNODES) {
#pragma unroll
    for (int r = 0; r < RREL; r++) v += cnt[r * NNODES + i];
  }
  __shared__ int sm[256];
  sm[t] = v;
  __syncthreads();
#pragma unroll
  for (int o = 1; o < 256; o <<= 1) {
    int x = (t >= o) ? sm[t - o] : 0;
    __syncthreads();
    sm[t] += x;
    __syncthreads();
  }
  if (i < NNODES) off[i] = sm[t] - v;
  if (t == 255) part[b] = sm[t];
}

// scan2: exclusive scan of part[0..SCAN_NB) in one block
__global__ __launch_bounds__(256) void scan2(int* __restrict__ part) {
  int t = threadIdx.x;
  int v = (t < SCAN_NB) ? part[t] : 0;
  __shared__ int sm[256];
  sm[t] = v;
  __syncthreads();
#pragma unroll
  for (int o = 1; o < 256; o <<= 1) {
    int x = (t >= o) ? sm[t - o] : 0;
    __syncthreads();
    sm[t] += x;
    __syncthreads();
  }
  if (t < SCAN_NB) part[t] = sm[t] - v;
}

// scan3: off[i] += part[block]; off[NNODES] = NEDGE
__global__ __launch_bounds__(256) void scan3(int* __restrict__ off, const int* __restrict__ part) {
  int i = blockIdx.x * 256 + threadIdx.x;
  if (i < NNODES) off[i] += part[blockIdx.x];
  if (i == 0) off[NNODES] = NEDGE;
}

// scatter: sorted[pos] = (r<<16)|src, scales[pos] = 1/cnt[r,d]
__global__ __launch_bounds__(256) void scatter_edges(
    const int* __restrict__ src, const int* __restrict__ dst, const int* __restrict__ et,
    const int* __restrict__ cnt, const int* __restrict__ off,
    int* __restrict__ fill, unsigned* __restrict__ sorted, float* __restrict__ scales) {
  int e = blockIdx.x * 256 + threadIdx.x;
  if (e >= NEDGE) return;
  int d = dst[e], r = et[e], s = src[e];
  int pos = off[d] + atomicAdd(&fill[d], 1);
  sorted[pos] = (unsigned)s | ((unsigned)r << 16);
  scales[pos] = 1.0f / (float)cnt[r * NNODES + d];
}

// ---------------- fused layer1: root+bias + segmented mean-agg + relu -> bf16 -----
// one 64-lane wave per dst node, lane = channel
__global__ __launch_bounds__(256) void fused1(
    const int* __restrict__ off, const unsigned* __restrict__ sorted,
    const float* __restrict__ scales, const ushort* __restrict__ Y1,
    const float* __restrict__ b1, __hip_bfloat16* __restrict__ x1b) {
  int w = threadIdx.x >> 6, lane = threadIdx.x & 63;
  int d = blockIdx.x * 4 + w;           // 12500 blocks exact
  int s0 = off[d], s1 = off[d + 1];
  float acc = bfu(Y1[(size_t)d * 1088 + lane]) + b1[lane];
  for (int i = s0; i < s1; i++) {
    unsigned p = sorted[i];
    int srcn = p & 0xFFFF;
    int r = p >> 16;
    acc += bfu(Y1[(size_t)srcn * 1088 + 64 + r * 64 + lane]) * scales[i];
  }
  x1b[(size_t)d * 64 + lane] = __float2bfloat16(fmaxf(acc, 0.f));
}

// ---------------- fused layer2: root+bias + agg + softmax -> out ------------------
// one 64-lane wave per dst; lanes (half=lane>>5) process edges 2 at a time, j=lane&31
__global__ __launch_bounds__(256) void fused2(
    const int* __restrict__ off, const unsigned* __restrict__ sorted,
    const float* __restrict__ scales, const ushort* __restrict__ Y2,
    const float* __restrict__ b2, float* __restrict__ out) {
  int w = threadIdx.x >> 6, lane = threadIdx.x & 63;
  int d = blockIdx.x * 4 + w;           // 12500 blocks exact
  int j = lane & 31, half = lane >> 5;
  int s0 = off[d], s1 = off[d + 1];
  float acc = 0.f;
  for (int i = s0 + half; i < s1; i += 2) {
    unsigned p = sorted[i];
    acc += bfu(Y2[(size_t)(p & 0xFFFF) * 544 + 32 + (p >> 16) * 32 + j]) * scales[i];
  }
  acc += __shfl_xor(acc, 32);           // combine edge-halves
  float v = acc + bfu(Y2[(size_t)d * 544 + j]) + b2[j];
  float mx = v;
#pragma unroll
  for (int o = 16; o; o >>= 1) mx = fmaxf(mx, __shfl_xor(mx, o));
  float e = __expf(v - mx);
  float sum = e;
#pragma unroll
  for (int o = 16; o; o >>= 1) sum += __shfl_xor(sum, o);
  if (half == 0) out[(size_t)d * 32 + j] = e / sum;
}

// =================================================================================
extern "C" void kernel_launch(void* const* d_in, const int* in_sizes, int n_in,
                              void* d_out, int out_size, void* d_ws, size_t ws_size,
                              hipStream_t stream) {
  (void)in_sizes; (void)n_in; (void)out_size; (void)ws_size;
  const float* emb   = (const float*)d_in[0];
  const float* ipw   = (const float*)d_in[1];
  const float* ipb   = (const float*)d_in[2];
  const float* opw   = (const float*)d_in[3];
  const float* opb   = (const float*)d_in[4];
  const float* w1    = (const float*)d_in[5];
  const float* root1 = (const float*)d_in[6];
  const float* b1    = (const float*)d_in[7];
  const float* w2    = (const float*)d_in[8];
  const float* root2 = (const float*)d_in[9];
  const float* b2    = (const float*)d_in[10];
  const int*   eidx  = (const int*)d_in[11];
  const int*   etype = (const int*)d_in[12];
  const int* srcp = eidx;
  const int* dstp = eidx + NEDGE;

  unsigned char* ws = (unsigned char*)d_ws;
  size_t off_b = 0;
  auto alloc = [&](size_t bytes) {
    unsigned char* p = ws + off_b;
    off_b += (bytes + 255) & ~(size_t)255;
    return p;
  };

  // Region R reused sequentially: [embb 51.2MB | kv 102.4MB] -> Y1 108.8MB -> Y2 54.4MB
  unsigned char* R = alloc(153600000);
  __hip_bfloat16* embb = (__hip_bfloat16*)R;
  __hip_bfloat16* kv   = (__hip_bfloat16*)(R + 51200000);
  __hip_bfloat16* Y1   = (__hip_bfloat16*)R;
  __hip_bfloat16* Y2   = (__hip_bfloat16*)R;
  __hip_bfloat16* q0   = (__hip_bfloat16*)alloc(12800000);
  __hip_bfloat16* o0   = (__hip_bfloat16*)alloc(12800000);
  __hip_bfloat16* x0   = (__hip_bfloat16*)alloc(12800000);
  __hip_bfloat16* x1b  = (__hip_bfloat16*)alloc(6400000);
  int*            cnt  = (int*)alloc(3200000);
  int*            offs = (int*)alloc((NNODES + 1) * 4);
  int*            fill = (int*)alloc(NNODES * 4);
  int*            part = (int*)alloc(SCAN_NB * 4);
  unsigned*       sorted = (unsigned*)alloc(NEDGE * 4);
  float*          scales = (float*)alloc(NEDGE * 4);
  __hip_bfloat16* BTqkv = (__hip_bfloat16*)alloc(98304);
  __hip_bfloat16* BTout = (__hip_bfloat16*)alloc(32768);
  __hip_bfloat16* BT1   = (__hip_bfloat16*)alloc(278528);
  __hip_bfloat16* BT2   = (__hip_bfloat16*)alloc(69632);

  // 1) weight prep + input convert + CSR build
  prep_weights<<<dim3((241664 + 255) / 256), dim3(256), 0, stream>>>(
      ipw, opw, w1, root1, w2, root2, BTqkv, BTout, BT1, BT2);
  f2b_kernel<<<dim3(12500), dim3(256), 0, stream>>>(emb, embb);
  hipMemsetAsync(cnt, 0, (size_t)RREL * NNODES * sizeof(int), stream);
  hipMemsetAsync(fill, 0, (size_t)NNODES * sizeof(int), stream);
  count_edges<<<dim3((NEDGE + 255) / 256), dim3(256), 0, stream>>>(dstp, etype, cnt);
  scan1<<<dim3(SCAN_NB), dim3(256), 0, stream>>>(cnt, offs, part);
  scan2<<<dim3(1), dim3(256), 0, stream>>>(part);
  scan3<<<dim3(SCAN_NB), dim3(256), 0, stream>>>(offs, part);
  scatter_edges<<<dim3((NEDGE + 255) / 256), dim3(256), 0, stream>>>(
      srcp, dstp, etype, cnt, offs, fill, sorted, scales);

  // 2) KV projection: (200000 x 128) @ (128 x 256) -> kv
  gemm_mfma<128><<<dim3(1563, 2), dim3(256), 0, stream>>>(
      embb, BTqkv + 128 * 128, ipb + 128, kv, 200000, 256, 128, 256);

  // 3) Q at l=0 -> q0
  gemm_mfma<128><<<dim3(391, 1), dim3(256), 0, stream>>>(
      embb, BTqkv, ipb, q0, NNODES, 128, 128, 128);

  // 4) attention -> o0
  attn_kernel<<<dim3(25000), dim3(256), 0, stream>>>(q0, kv, o0);

  // 5) out_proj -> x0
  gemm_mfma<128><<<dim3(391, 1), dim3(256), 0, stream>>>(
      o0, BTout, opb, x0, NNODES, 128, 128, 128);

  // 6) Y1 = x0 @ [root1 | W1_r]: (50000 x 128) @ (128 x 1088)
  gemm_mfma<128><<<dim3(391, 9), dim3(256), 0, stream>>>(
      x0, BT1, nullptr, Y1, NNODES, 1088, 128, 1088);

  // 7) fused layer1 -> x1b (bf16)
  fused1<<<dim3(NNODES / 4), dim3(256), 0, stream>>>(
      offs, sorted, scales, (const ushort*)Y1, b1, x1b);

  // 8) Y2 = x1b @ [root2 | W2_r]: (50000 x 64) @ (64 x 544)
  gemm_mfma<64><<<dim3(391, 5), dim3(256), 0, stream>>>(
      x1b, BT2, nullptr, Y2, NNODES, 544, 64, 544);

  // 9) fused layer2 + softmax -> out
  fused2<<<dim3(NNODES / 4), dim3(256), 0, stream>>>(
      offs, sorted, scales, (const ushort*)Y2, b2, (float*)d_out);
}

// Round 4
// 394.855 us; speedup vs baseline: 2.9964x; 1.3430x over previous
//
#include <hip/hip_runtime.h>
#include <hip/hip_bf16.h>
#include <math.h>

#define NNODES 50000
#define NEDGE 625000
#define RREL 16
#define SCAN_NB 196   // ceil(50000/256)

typedef __attribute__((ext_vector_type(8))) short short8;
typedef __attribute__((ext_vector_type(4))) float f32x4;

__device__ __forceinline__ float bfu(ushort u) {
  return __uint_as_float(((unsigned)u) << 16);
}
__device__ __forceinline__ ushort f2b(float f) {
  __hip_bfloat16 h = __float2bfloat16(f);
  return *(ushort*)&h;
}

// ---------------- weight prep: bf16, B stored transposed (N x K, K contiguous) ----
__global__ __launch_bounds__(256) void prep_weights(
    const float* __restrict__ ipw, const float* __restrict__ opw,
    const float* __restrict__ w1, const float* __restrict__ root1,
    const float* __restrict__ w2, const float* __restrict__ root2,
    __hip_bfloat16* __restrict__ BTqkv, __hip_bfloat16* __restrict__ BTout,
    __hip_bfloat16* __restrict__ BT1, __hip_bfloat16* __restrict__ BT2) {
  int i = blockIdx.x * 256 + threadIdx.x;
  if (i < 49152) {
    BTqkv[i] = __float2bfloat16(ipw[i]);
  } else if (i < 65536) {
    int j = i - 49152;
    BTout[j] = __float2bfloat16(opw[j]);
  } else if (i < 65536 + 139264) {
    int j = i - 65536; int c = j / 128, k = j % 128;
    float v;
    if (c < 64) v = root1[k * 64 + c];
    else { int r = (c - 64) >> 6, o = (c - 64) & 63; v = w1[r * 8192 + k * 64 + o]; }
    BT1[j] = __float2bfloat16(v);
  } else if (i < 65536 + 139264 + 34816) {
    int j = i - 65536 - 139264; int c = j / 64, k = j % 64;
    float v;
    if (c < 32) v = root2[k * 32 + c];
    else { int r = (c - 32) >> 5, o = (c - 32) & 31; v = w2[r * 2048 + k * 32 + o]; }
    BT2[j] = __float2bfloat16(v);
  }
}

// ---------------- bf16 MFMA GEMM: C[M,N] = A[M,K] @ BT[N,K]^T (+bias) -------------
// 128x128 tile, 4 waves. A may be f32 (converted during staging). Coalesced
// epilogue: C-tile staged in LDS (reusing A/B panels), stored as int4.
// Mq: effective M for col-block 0 (QKV merge); pass M for normal GEMMs.
template <int K, bool AF32>
__global__ __launch_bounds__(256) void gemm_mfma(
    const void* __restrict__ Av, const __hip_bfloat16* __restrict__ BT,
    const float* __restrict__ bias, __hip_bfloat16* __restrict__ C,
    int M, int Mq, int N, int lda, int ldc) {
  constexpr int CPR = K / 8;  // 16B (8-elem) chunks per row
  __shared__ ushort smem[2 * 128 * K];
  ushort* As = smem;
  ushort* Bs = smem + 128 * K;
  const int t = threadIdx.x;
  const long row0 = (long)blockIdx.x * 128;
  const int col0 = blockIdx.y * 128;
  const int Meff = (blockIdx.y == 0) ? Mq : M;
  if (row0 >= Meff) return;

#pragma unroll
  for (int c = t; c < 128 * CPR; c += 256) {
    int r = c / CPR, cc = c % CPR;
    long gm = row0 + r;
    int4 v = make_int4(0, 0, 0, 0);
    if (gm < Meff) {
      if constexpr (AF32) {
        const float* ap = (const float*)Av + gm * lda + cc * 8;
        float4 f0 = *(const float4*)ap;
        float4 f1 = *(const float4*)(ap + 4);
        v.x = (int)f2b(f0.x) | ((int)f2b(f0.y) << 16);
        v.y = (int)f2b(f0.z) | ((int)f2b(f0.w) << 16);
        v.z = (int)f2b(f1.x) | ((int)f2b(f1.y) << 16);
        v.w = (int)f2b(f1.z) | ((int)f2b(f1.w) << 16);
      } else {
        v = *(const int4*)((const ushort*)Av + gm * lda + cc * 8);
      }
    }
    *(int4*)(As + r * K + ((cc ^ (r & 7)) * 8)) = v;
  }
#pragma unroll
  for (int c = t; c < 128 * CPR; c += 256) {
    int r = c / CPR, cc = c % CPR;
    int gn = col0 + r;
    int4 v = make_int4(0, 0, 0, 0);
    if (gn < N) v = *(const int4*)(BT + (long)gn * K + cc * 8);
    *(int4*)(Bs + r * K + ((cc ^ (r & 7)) * 8)) = v;
  }
  __syncthreads();

  const int lane = t & 63, w = t >> 6;
  const int wr = (w >> 1) * 64, wc = (w & 1) * 64;
  const int lrow = lane & 15, lk = lane >> 4;
  f32x4 acc[4][4];
#pragma unroll
  for (int i = 0; i < 4; i++)
#pragma unroll
    for (int j = 0; j < 4; j++) acc[i][j] = (f32x4){0.f, 0.f, 0.f, 0.f};

#pragma unroll
  for (int k0 = 0; k0 < K; k0 += 32) {
    const int cb = k0 / 8 + lk;
    short8 af[4], bfr[4];
#pragma unroll
    for (int i = 0; i < 4; i++) {
      int ra = wr + i * 16 + lrow;
      af[i] = *(const short8*)(As + ra * K + ((cb ^ (ra & 7)) * 8));
      int rb = wc + i * 16 + lrow;
      bfr[i] = *(const short8*)(Bs + rb * K + ((cb ^ (rb & 7)) * 8));
    }
#pragma unroll
    for (int i = 0; i < 4; i++)
#pragma unroll
      for (int j = 0; j < 4; j++)
        acc[i][j] = __builtin_amdgcn_mfma_f32_16x16x32_bf16(af[i], bfr[j], acc[i][j], 0, 0, 0);
  }

  // ---- epilogue: stage bf16 C-tile in LDS, then coalesced int4 stores ----
  __syncthreads();
  ushort* Cs = smem;  // 128*128 ushorts = 32KB <= 2*128*K
#pragma unroll
  for (int j = 0; j < 4; j++) {
    int coll = wc + j * 16 + lrow;
    float bv = bias ? bias[col0 + coll] : 0.f;
#pragma unroll
    for (int i = 0; i < 4; i++) {
      int rbase = wr + i * 16 + lk * 4;
#pragma unroll
      for (int q = 0; q < 4; q++)
        Cs[(rbase + q) * 128 + coll] = f2b(acc[i][j][q] + bv);
    }
  }
  __syncthreads();
#pragma unroll
  for (int idx = t; idx < 128 * 16; idx += 256) {
    int r = idx >> 4, k = idx & 15;
    long gm = row0 + r;
    int col = col0 + k * 8;
    if (gm < Meff && col < N)
      *(int4*)((ushort*)C + gm * ldc + col) = *(const int4*)(Cs + r * 128 + k * 8);
  }
}

// ---------------- attention (only l=0 of output needed) ---------------------------
// qkv: row (l*NNODES+n), cols: [0,128)=q, [128,256)=k, [256,384)=v, ld=384
__global__ __launch_bounds__(256) void attn_kernel(
    const __hip_bfloat16* __restrict__ qkv, __hip_bfloat16* __restrict__ o0) {
  int t = threadIdx.x;
  int n = blockIdx.x * 2 + (t >> 7);
  int ch = t & 127;
  float q = __bfloat162float(qkv[(size_t)n * 384 + ch]);
  float s[4];
#pragma unroll
  for (int m = 0; m < 4; m++) {
    float kk = __bfloat162float(qkv[(size_t)(m * NNODES + n) * 384 + 128 + ch]);
    float p = q * kk;
#pragma unroll
    for (int off = 16; off; off >>= 1) p += __shfl_xor(p, off);
    s[m] = p * 0.17677669529663687f;
  }
  float mx = fmaxf(fmaxf(s[0], s[1]), fmaxf(s[2], s[3]));
  float e[4], sum = 0.f;
#pragma unroll
  for (int m = 0; m < 4; m++) { e[m] = __expf(s[m] - mx); sum += e[m]; }
  float inv = 1.0f / sum;
  float out = 0.f;
#pragma unroll
  for (int m = 0; m < 4; m++)
    out += e[m] * inv * __bfloat162float(qkv[(size_t)(m * NNODES + n) * 384 + 256 + ch]);
  o0[(size_t)n * 128 + ch] = __float2bfloat16(out);
}

// ---------------- edge counts per (r, dst) ---------------------------------------
__global__ __launch_bounds__(256) void count_edges(
    const int* __restrict__ dst, const int* __restrict__ et, int* __restrict__ cnt) {
  int e = blockIdx.x * 256 + threadIdx.x;
  if (e < NEDGE) atomicAdd(&cnt[et[e] * NNODES + dst[e]], 1);
}

// ---------------- CSR build ------------------------------------------------------
__global__ __launch_bounds__(256) void scan1(
    const int* __restrict__ cnt, int* __restrict__ off, int* __restrict__ part) {
  int t = threadIdx.x, b = blockIdx.x;
  int i = b * 256 + t;
  int v = 0;
  if (i < NNODES) {
#pragma unroll
    for (int r = 0; r < RREL; r++) v += cnt[r * NNODES + i];
  }
  __shared__ int sm[256];
  sm[t] = v;
  __syncthreads();
#pragma unroll
  for (int o = 1; o < 256; o <<= 1) {
    int x = (t >= o) ? sm[t - o] : 0;
    __syncthreads();
    sm[t] += x;
    __syncthreads();
  }
  if (i < NNODES) off[i] = sm[t] - v;
  if (t == 255) part[b] = sm[t];
}

__global__ __launch_bounds__(256) void scan2(int* __restrict__ part) {
  int t = threadIdx.x;
  int v = (t < SCAN_NB) ? part[t] : 0;
  __shared__ int sm[256];
  sm[t] = v;
  __syncthreads();
#pragma unroll
  for (int o = 1; o < 256; o <<= 1) {
    int x = (t >= o) ? sm[t - o] : 0;
    __syncthreads();
    sm[t] += x;
    __syncthreads();
  }
  if (t < SCAN_NB) part[t] = sm[t] - v;
}

__global__ __launch_bounds__(256) void scan3(int* __restrict__ off, const int* __restrict__ part) {
  int i = blockIdx.x * 256 + threadIdx.x;
  if (i < NNODES) off[i] += part[blockIdx.x];
  if (i == 0) off[NNODES] = NEDGE;
}

__global__ __launch_bounds__(256) void scatter_edges(
    const int* __restrict__ src, const int* __restrict__ dst, const int* __restrict__ et,
    const int* __restrict__ cnt, const int* __restrict__ off,
    int* __restrict__ fill, unsigned* __restrict__ sorted, float* __restrict__ scales) {
  int e = blockIdx.x * 256 + threadIdx.x;
  if (e >= NEDGE) return;
  int d = dst[e], r = et[e], s = src[e];
  int pos = off[d] + atomicAdd(&fill[d], 1);
  sorted[pos] = (unsigned)s | ((unsigned)r << 16);
  scales[pos] = 1.0f / (float)cnt[r * NNODES + d];
}

// ---------------- fused layer1: root+bias + segmented mean-agg + relu -> bf16 -----
__global__ __launch_bounds__(256) void fused1(
    const int* __restrict__ off, const unsigned* __restrict__ sorted,
    const float* __restrict__ scales, const ushort* __restrict__ Y1,
    const float* __restrict__ b1, __hip_bfloat16* __restrict__ x1b) {
  int w = threadIdx.x >> 6, lane = threadIdx.x & 63;
  int d = blockIdx.x * 4 + w;
  int s0 = off[d], s1 = off[d + 1];
  float acc = bfu(Y1[(size_t)d * 1088 + lane]) + b1[lane];
  for (int i = s0; i < s1; i++) {
    unsigned p = sorted[i];
    acc += bfu(Y1[(size_t)(p & 0xFFFF) * 1088 + 64 + (p >> 16) * 64 + lane]) * scales[i];
  }
  x1b[(size_t)d * 64 + lane] = __float2bfloat16(fmaxf(acc, 0.f));
}

// ---------------- fused layer2: root+bias + agg + softmax -> out ------------------
__global__ __launch_bounds__(256) void fused2(
    const int* __restrict__ off, const unsigned* __restrict__ sorted,
    const float* __restrict__ scales, const ushort* __restrict__ Y2,
    const float* __restrict__ b2, float* __restrict__ out) {
  int w = threadIdx.x >> 6, lane = threadIdx.x & 63;
  int d = blockIdx.x * 4 + w;
  int j = lane & 31, half = lane >> 5;
  int s0 = off[d], s1 = off[d + 1];
  float acc = 0.f;
  for (int i = s0 + half; i < s1; i += 2) {
    unsigned p = sorted[i];
    acc += bfu(Y2[(size_t)(p & 0xFFFF) * 544 + 32 + (p >> 16) * 32 + j]) * scales[i];
  }
  acc += __shfl_xor(acc, 32);
  float v = acc + bfu(Y2[(size_t)d * 544 + j]) + b2[j];
  float mx = v;
#pragma unroll
  for (int o = 16; o; o >>= 1) mx = fmaxf(mx, __shfl_xor(mx, o));
  float e = __expf(v - mx);
  float sum = e;
#pragma unroll
  for (int o = 16; o; o >>= 1) sum += __shfl_xor(sum, o);
  if (half == 0) out[(size_t)d * 32 + j] = e / sum;
}

// =================================================================================
extern "C" void kernel_launch(void* const* d_in, const int* in_sizes, int n_in,
                              void* d_out, int out_size, void* d_ws, size_t ws_size,
                              hipStream_t stream) {
  (void)in_sizes; (void)n_in; (void)out_size; (void)ws_size;
  const float* emb   = (const float*)d_in[0];
  const float* ipw   = (const float*)d_in[1];
  const float* ipb   = (const float*)d_in[2];
  const float* opw   = (const float*)d_in[3];
  const float* opb   = (const float*)d_in[4];
  const float* w1    = (const float*)d_in[5];
  const float* root1 = (const float*)d_in[6];
  const float* b1    = (const float*)d_in[7];
  const float* w2    = (const float*)d_in[8];
  const float* root2 = (const float*)d_in[9];
  const float* b2    = (const float*)d_in[10];
  const int*   eidx  = (const int*)d_in[11];
  const int*   etype = (const int*)d_in[12];
  const int* srcp = eidx;
  const int* dstp = eidx + NEDGE;

  unsigned char* ws = (unsigned char*)d_ws;
  size_t off_b = 0;
  auto alloc = [&](size_t bytes) {
    unsigned char* p = ws + off_b;
    off_b += (bytes + 255) & ~(size_t)255;
    return p;
  };

  // Region R reused sequentially: qkv 153.6MB -> Y1 108.8MB -> Y2 54.4MB
  unsigned char* R = alloc(153600000);
  __hip_bfloat16* qkv = (__hip_bfloat16*)R;
  __hip_bfloat16* Y1  = (__hip_bfloat16*)R;
  __hip_bfloat16* Y2  = (__hip_bfloat16*)R;
  __hip_bfloat16* o0  = (__hip_bfloat16*)alloc(12800000);
  __hip_bfloat16* x0  = (__hip_bfloat16*)alloc(12800000);
  __hip_bfloat16* x1b = (__hip_bfloat16*)alloc(6400000);
  int*            cnt = (int*)alloc(3200000);
  int*            offs = (int*)alloc((NNODES + 1) * 4);
  int*            fill = (int*)alloc(NNODES * 4);
  int*            part = (int*)alloc(SCAN_NB * 4);
  unsigned*       sorted = (unsigned*)alloc(NEDGE * 4);
  float*          scales = (float*)alloc(NEDGE * 4);
  __hip_bfloat16* BTqkv = (__hip_bfloat16*)alloc(98304);
  __hip_bfloat16* BTout = (__hip_bfloat16*)alloc(32768);
  __hip_bfloat16* BT1   = (__hip_bfloat16*)alloc(278528);
  __hip_bfloat16* BT2   = (__hip_bfloat16*)alloc(69632);

  // 1) weight prep + CSR build
  prep_weights<<<dim3((241664 + 255) / 256), dim3(256), 0, stream>>>(
      ipw, opw, w1, root1, w2, root2, BTqkv, BTout, BT1, BT2);
  hipMemsetAsync(cnt, 0, (size_t)RREL * NNODES * sizeof(int), stream);
  hipMemsetAsync(fill, 0, (size_t)NNODES * sizeof(int), stream);
  count_edges<<<dim3((NEDGE + 255) / 256), dim3(256), 0, stream>>>(dstp, etype, cnt);
  scan1<<<dim3(SCAN_NB), dim3(256), 0, stream>>>(cnt, offs, part);
  scan2<<<dim3(1), dim3(256), 0, stream>>>(part);
  scan3<<<dim3(SCAN_NB), dim3(256), 0, stream>>>(offs, part);
  scatter_edges<<<dim3((NEDGE + 255) / 256), dim3(256), 0, stream>>>(
      srcp, dstp, etype, cnt, offs, fill, sorted, scales);

  // 2) QKV: (200000 x 128 f32) @ (128 x 384) -> qkv; Q strip only rows < 50000
  gemm_mfma<128, true><<<dim3(1563, 3), dim3(256), 0, stream>>>(
      emb, BTqkv, ipb, qkv, 200000, NNODES, 384, 128, 384);

  // 3) attention -> o0
  attn_kernel<<<dim3(25000), dim3(256), 0, stream>>>(qkv, o0);

  // 4) out_proj -> x0
  gemm_mfma<128, false><<<dim3(391, 1), dim3(256), 0, stream>>>(
      o0, BTout, opb, x0, NNODES, NNODES, 128, 128, 128);

  // 5) Y1 = x0 @ [root1 | W1_r]: (50000 x 128) @ (128 x 1088)
  gemm_mfma<128, false><<<dim3(391, 9), dim3(256), 0, stream>>>(
      x0, BT1, nullptr, Y1, NNODES, NNODES, 1088, 128, 1088);

  // 6) fused layer1 -> x1b
  fused1<<<dim3(NNODES / 4), dim3(256), 0, stream>>>(
      offs, sorted, scales, (const ushort*)Y1, b1, x1b);

  // 7) Y2 = x1b @ [root2 | W2_r]: (50000 x 64) @ (64 x 544)
  gemm_mfma<64, false><<<dim3(391, 5), dim3(256), 0, stream>>>(
      x1b, BT2, nullptr, Y2, NNODES, NNODES, 544, 64, 544);

  // 8) fused layer2 + softmax -> out
  fused2<<<dim3(NNODES / 4), dim3(256), 0, stream>>>(
      offs, sorted, scales, (const ushort*)Y2, b2, (float*)d_out);
}